// Round 4
// baseline (648.560 us; speedup 1.0000x reference)
//
#include <hip/hip_runtime.h>

// VQEmbedding forward (TRAINING=True):
//   z_e_x [32,256,64,64] f32, codebook [512,256] f32, labels [32] i32
//   out = concat(z_q_x, z_q_x_bar), each [32,256,64,64] f32 — both equal
//   codebook[argmin] in the forward pass (x+(c-x) roundoff ~4e-7 << thr).
//
// Reference-exact fp32 distance emulation (passed R2/R3):
//   dist = fl( fl(insq + cbsq_k) - 2*dot_k ), dot = ascending-d fp32 FMA chain,
//   insq = fp64 ascending-d fma -> fp32, argmin strict < ascending k.
//
// R4: R3's wave-uniform weight loads compiled to s_load — a 1-deep scalar
// pipeline (SGPR budget) with a lgkmcnt(0) wait per 4-d group. Convert the
// weight path to deep-queue VMEM broadcast float4 loads from a pre-packed
// per-class layout wpk[class][d][64] (pad codes: w=0, wsq=1e30 -> never win).
// Opaque-zero VGPR added to the address stops the compiler re-scalarizing.

#define D       256
#define KCODES  512
#define HW      4096
#define BATCH   32
#define NPTS    (BATCH * HW)   // 131072
#define NCLS    10
#define WPW     16             // codes per wave (4*16 = 64 padded slots)

__constant__ int c_cls_start[11] = {0, 51, 101, 151, 201, 251, 301, 352, 402, 452, 502};

// wpk[c][d][64]: column j = cb[c_start+j][d], zero-padded past class count
__global__ __launch_bounds__(64) void pack_kernel(const float* __restrict__ cb,
                                                  float* __restrict__ wpk) {
    const int c = blockIdx.x >> 8;        // 0..9
    const int d = blockIdx.x & 255;
    const int j = threadIdx.x;            // 0..63
    const int c0 = c_cls_start[c], cnt = c_cls_start[c + 1] - c0;
    float v = 0.0f;
    if (j < cnt) v = cb[(size_t)(c0 + j) * D + d];
    wpk[((size_t)c * D + d) * 64 + j] = v;
}

// wsq[c][64] = fl32( fp64 sum_d cb[c0+j][d]^2 ), 1e30 padding (pads never win)
__global__ __launch_bounds__(64) void wsq_kernel(const float* __restrict__ cb,
                                                 float* __restrict__ wsq) {
    const int c = blockIdx.x;             // 0..9
    const int j = threadIdx.x;            // 0..63
    const int c0 = c_cls_start[c], cnt = c_cls_start[c + 1] - c0;
    float r = 1e30f;
    if (j < cnt) {
        const float* __restrict__ row = cb + (size_t)(c0 + j) * D;
        double s = 0.0;
        for (int d = 0; d < D; ++d) { double a = (double)row[d]; s = fma(a, a, s); }
        r = (float)s;
    }
    wsq[c * 64 + j] = r;
}

__global__ __launch_bounds__(256, 8) void vq_kernel(const float* __restrict__ z,
                                                    const int* __restrict__ labels,
                                                    const float* __restrict__ wpk,
                                                    const float* __restrict__ wsq,
                                                    float* __restrict__ out) {
    const int lane = threadIdx.x & 63;
    const int w    = __builtin_amdgcn_readfirstlane(threadIdx.x >> 6);  // 0..3
    const int b    = blockIdx.x >> 6;                  // 64 blocks per image
    const int hw   = ((blockIdx.x & 63) << 6) | lane;  // this lane's point
    const int lab  = __builtin_amdgcn_readfirstlane(labels[b]);

    int vz;
    asm volatile("v_mov_b32 %0, 0" : "=v"(vz));  // opaque 0 -> force VMEM path

    const float* __restrict__ xp = z + (size_t)b * (D * HW) + hw;   // x[d]=xp[d*HW]
    const float4* __restrict__ wp =
        (const float4*)(wpk + ((size_t)lab * D) * 64 + (w * WPW) + vz);
    // row d of this wave's slice: wp[d*16 + 0..3]

    float acc[WPW];
#pragma unroll
    for (int j = 0; j < WPW; ++j) acc[j] = 0.0f;

    double xsq = 0.0;  // ||x||^2 in fp64, ascending d (identical to R2/R3)

    float xb[4];
#pragma unroll
    for (int i = 0; i < 4; ++i) xb[i] = xp[(size_t)i * HW];

    for (int d = 0; d < D; d += 4) {
        float xn[4];
#pragma unroll
        for (int i = 0; i < 4; ++i) {
            int dn = (d + 4 + i) & (D - 1);  // wrap on last chunk (harmless reload)
            xn[i] = xp[(size_t)dn * HW];
        }
#pragma unroll
        for (int i = 0; i < 4; ++i) {
            const float4 w0 = wp[(size_t)(d + i) * 16 + 0];
            const float4 w1 = wp[(size_t)(d + i) * 16 + 1];
            const float4 w2 = wp[(size_t)(d + i) * 16 + 2];
            const float4 w3 = wp[(size_t)(d + i) * 16 + 3];
            const float x = xb[i];
            xsq = fma((double)x, (double)x, xsq);
            acc[ 0] = fmaf(x, w0.x, acc[ 0]);
            acc[ 1] = fmaf(x, w0.y, acc[ 1]);
            acc[ 2] = fmaf(x, w0.z, acc[ 2]);
            acc[ 3] = fmaf(x, w0.w, acc[ 3]);
            acc[ 4] = fmaf(x, w1.x, acc[ 4]);
            acc[ 5] = fmaf(x, w1.y, acc[ 5]);
            acc[ 6] = fmaf(x, w1.z, acc[ 6]);
            acc[ 7] = fmaf(x, w1.w, acc[ 7]);
            acc[ 8] = fmaf(x, w2.x, acc[ 8]);
            acc[ 9] = fmaf(x, w2.y, acc[ 9]);
            acc[10] = fmaf(x, w2.z, acc[10]);
            acc[11] = fmaf(x, w2.w, acc[11]);
            acc[12] = fmaf(x, w3.x, acc[12]);
            acc[13] = fmaf(x, w3.y, acc[13]);
            acc[14] = fmaf(x, w3.z, acc[14]);
            acc[15] = fmaf(x, w3.w, acc[15]);
        }
#pragma unroll
        for (int i = 0; i < 4; ++i) xb[i] = xn[i];
    }

    // Emulated reference distance; local argmin over this wave's 16 code slots
    const float insq = (float)xsq;
    const int jbase = w * WPW;                       // local slot index base
    const float* __restrict__ wsqc = wsq + lab * 64 + jbase;  // uniform, tiny
    float best = __builtin_inff();
    int bi = jbase;
#pragma unroll
    for (int j = 0; j < WPW; ++j) {
        float T    = insq + wsqc[j];                 // fp32 add, RNE
        float dist = fmaf(-2.0f, acc[j], T);         // == fl(T - 2*acc)
        if (dist < best) { best = dist; bi = jbase + j; }  // pads (1e30) never win
    }

    // Cross-wave argmin via LDS (ascending w + strict < == lowest-index tie-break)
    __shared__ float sd[4][64];
    __shared__ int   si[4][64];
    sd[w][lane] = best;
    si[w][lane] = bi;
    __syncthreads();
    float fb = sd[0][lane];
    int   fi = si[0][lane];
#pragma unroll
    for (int w2 = 1; w2 < 4; ++w2) {
        float dv = sd[w2][lane];
        if (dv < fb) { fb = dv; fi = si[w2][lane]; }
    }

    // Epilogue: out0 = out1 = codebook row (from wpk); wave w writes d in [64w,64w+64)
    float* __restrict__ o0 = out + (size_t)b * (D * HW) + hw;
    float* __restrict__ o1 = o0 + (size_t)NPTS * D;
    const float* __restrict__ wrb = wpk + ((size_t)lab * D) * 64 + fi;
    const int d0 = w * 64;
    for (int d = d0; d < d0 + 64; ++d) {
        float v = wrb[(size_t)d * 64];   // lanes within 256B window -> 2 lines, L1
        o0[(size_t)d * HW] = v;
        o1[(size_t)d * HW] = v;
    }
}

extern "C" void kernel_launch(void* const* d_in, const int* in_sizes, int n_in,
                              void* d_out, int out_size, void* d_ws, size_t ws_size,
                              hipStream_t stream) {
    const float* z      = (const float*)d_in[0];
    const float* cb     = (const float*)d_in[1];
    const int*   labels = (const int*)d_in[2];
    float* out = (float*)d_out;

    float* wpk = (float*)d_ws;                    // 10*256*64 f32 = 640 KB
    float* wsq = wpk + (size_t)NCLS * D * 64;     // 10*64 f32

    hipLaunchKernelGGL(pack_kernel, dim3(NCLS * 256), dim3(64), 0, stream, cb, wpk);
    hipLaunchKernelGGL(wsq_kernel, dim3(NCLS), dim3(64), 0, stream, cb, wsq);
    hipLaunchKernelGGL(vq_kernel, dim3(NPTS / 64), dim3(256), 0, stream,
                       z, labels, wpk, wsq, out);
}